// Round 9
// baseline (205.744 us; speedup 1.0000x reference)
//
#include <hip/hip_runtime.h>
#include <math.h>

#define HWSZ 4096   // 64*64
// 1/sqrt(32) * log2(e): scores come out pre-multiplied by log2(e), so softmax
// uses p = exp2(S) (single v_exp_f32) -- mathematically identical.
#define QSCALE_L2E 0.25501988932587245f

typedef __bf16 bf16x2 __attribute__((ext_vector_type(2)));
typedef __bf16 bf16x4 __attribute__((ext_vector_type(4)));
typedef __bf16 bf16x8 __attribute__((ext_vector_type(8)));
typedef float  f32x4  __attribute__((ext_vector_type(4)));

// ---------------- scrambled-token LayerNorm, strip version ----------------
__global__ __launch_bounds__(256) void ln_qn_kernel(
    const float* __restrict__ F, const float* __restrict__ lnw,
    const float* __restrict__ lnb, __bf16* __restrict__ qnb)
{
  __shared__ float sm[16*269];         // [c16] stride 269, [py] stride 67, [x]
  int blk = blockIdx.x;                // b*256 + wy*16 + t
  int b = blk >> 8, wy = (blk >> 4) & 15, t = blk & 15;
  int tid = threadIdx.x;
  const float* Fb = F + ((size_t)(b*256 + t*16))*HWSZ + (wy*4)*64;
  int py = tid >> 6, x = tid & 63;
  #pragma unroll
  for (int j = 0; j < 16; ++j)
    sm[j*269 + py*67 + x] = Fb[(size_t)j*HWSZ + py*64 + x];
  __syncthreads();
  int wx = tid >> 4, cl = tid & 15;    // window wx, channel-lane cl
  float vals[16], s1 = 0.f, s2 = 0.f;
  #pragma unroll
  for (int p = 0; p < 16; ++p) {
    float v = sm[cl*269 + (p >> 2)*67 + wx*4 + (p & 3)];
    vals[p] = v; s1 += v; s2 += v*v;
  }
  #pragma unroll
  for (int m = 1; m < 16; m <<= 1) { s1 += __shfl_xor(s1, m); s2 += __shfl_xor(s2, m); }
  float mean = s1 * (1.f/256.f);
  float var  = s2 * (1.f/256.f) - mean*mean;
  float rstd = rsqrtf(var + 1e-5f);
  __bf16* outp = qnb + (((size_t)(b*256 + wy*16 + wx))*16 + t)*256 + cl*16;
  bf16x8 o0, o1;
  #pragma unroll
  for (int p = 0; p < 8; ++p) {
    o0[p] = (__bf16)((vals[p]  -mean)*rstd*lnw[cl*16+p]   + lnb[cl*16+p]);
    o1[p] = (__bf16)((vals[p+8]-mean)*rstd*lnw[cl*16+p+8] + lnb[cl*16+p+8]);
  }
  *(bf16x8*)outp = o0;
  *(bf16x8*)(outp+8) = o1;
}

// ---------------- fused pools: thread = 2x2 mid patch -> 1 glb elem ----------------
__global__ __launch_bounds__(256) void pool_kernel(
    const float* __restrict__ F, float* __restrict__ mid, float* __restrict__ glb)
{
  int bc = blockIdx.x;                  // b*256 + c
  int t = threadIdx.x;
  int gy = t >> 4, gx = t & 15;
  const float* p = F + (size_t)bc*HWSZ + (gy*4)*64 + gx*4;
  float4 r0 = *(const float4*)(p);
  float4 r1 = *(const float4*)(p + 64);
  float4 r2 = *(const float4*)(p + 128);
  float4 r3 = *(const float4*)(p + 192);
  float m00 = 0.25f*(r0.x + r0.y + r1.x + r1.y);
  float m01 = 0.25f*(r0.z + r0.w + r1.z + r1.w);
  float m10 = 0.25f*(r2.x + r2.y + r3.x + r3.y);
  float m11 = 0.25f*(r2.z + r2.w + r3.z + r3.w);
  float* mp = mid + (size_t)bc*1024 + (gy*2)*32 + gx*2;
  *(float2*)mp        = make_float2(m00, m01);
  *(float2*)(mp + 32) = make_float2(m10, m11);
  glb[(size_t)bc*256 + gy*16 + gx] = 0.25f*(m00 + m01 + m10 + m11);
}

// ---------------- one-time: both weight transposes in one dispatch ----------------
__global__ __launch_bounds__(256) void transpose_ws(
    const float* __restrict__ Wqkv, const float* __restrict__ Wout,
    __bf16* __restrict__ WT, __bf16* __restrict__ WoT)
{
  __shared__ float T[64][68];
  int bx = blockIdx.x;
  const float* W; __bf16* D; int ncols, n0;
  if (bx < 12) { W = Wqkv; D = WT;  ncols = 768; n0 = bx*64; }
  else         { W = Wout; D = WoT; ncols = 256; n0 = (bx-12)*64; }
  int k0 = blockIdx.y*64;
  int tid = threadIdx.x;
  int c4 = (tid & 15)*4, rr = tid >> 4;
  #pragma unroll
  for (int p = 0; p < 4; ++p) {
    int row = p*16 + rr;
    float4 v = *(const float4*)(W + (size_t)(k0+row)*ncols + n0 + c4);
    T[c4+0][row] = v.x; T[c4+1][row] = v.y; T[c4+2][row] = v.z; T[c4+3][row] = v.w;
  }
  __syncthreads();
  #pragma unroll
  for (int p = 0; p < 4; ++p) {
    int cc = p*16 + rr;
    bf16x4 o;
    o[0] = (__bf16)T[cc][c4+0]; o[1] = (__bf16)T[cc][c4+1];
    o[2] = (__bf16)T[cc][c4+2]; o[3] = (__bf16)T[cc][c4+3];
    *(bf16x4*)(D + (size_t)(n0+cc)*256 + k0 + c4) = o;
  }
}

// ---------------- pooled tokens: transpose [c][tok] fp32 -> [tok][c] bf16 ----------------
__global__ __launch_bounds__(256) void transpose_tok(
    const float* __restrict__ mid, const float* __restrict__ glb,
    __bf16* __restrict__ mgt)
{
  __shared__ float T[64][68];
  int t0 = blockIdx.x*64, c0 = blockIdx.y*64, b = blockIdx.z;
  const float* src; int stride, toff;
  if (t0 < 1024) { src = mid + ((size_t)(b*256 + c0))*1024; stride = 1024; toff = t0; }
  else           { src = glb + ((size_t)(b*256 + c0))*256;  stride = 256;  toff = t0 - 1024; }
  int tid = threadIdx.x;
  int c4 = (tid & 15)*4, rr = tid >> 4;
  #pragma unroll
  for (int p = 0; p < 4; ++p) {
    int row = p*16 + rr;                 // channel offset
    float4 v = *(const float4*)(src + (size_t)row*stride + toff + c4);
    T[c4+0][row] = v.x; T[c4+1][row] = v.y; T[c4+2][row] = v.z; T[c4+3][row] = v.w;
  }
  __syncthreads();
  #pragma unroll
  for (int p = 0; p < 4; ++p) {
    int tt = p*16 + rr;                  // token offset
    bf16x4 o;
    o[0] = (__bf16)T[tt][c4+0]; o[1] = (__bf16)T[tt][c4+1];
    o[2] = (__bf16)T[tt][c4+2]; o[3] = (__bf16)T[tt][c4+3];
    *(bf16x4*)(mgt + ((size_t)b*1280 + t0 + tt)*256 + c0 + c4) = o;
  }
}

// ---------------- q GEMM (MFMA, swapped operands); scale includes log2(e) ----------------
__global__ __launch_bounds__(256) void gemm_q_mfma(
    const __bf16* __restrict__ qnb, const __bf16* __restrict__ WT,
    const float* __restrict__ qkvb, __bf16* __restrict__ qbf)
{
  int tid = threadIdx.x, wv = tid >> 6, lane = tid & 63;
  int col = lane & 15, quad = lane >> 4;
  int win = blockIdx.x*2 + (wv >> 1);
  int nbase = (wv & 1)*8;
  bf16x8 bq[8];
  const __bf16* qp = qnb + ((size_t)win*16 + col)*256 + quad*8;
  #pragma unroll
  for (int kk = 0; kk < 8; ++kk) bq[kk] = *(const bf16x8*)(qp + kk*32);
  const f32x4 zero = {0.f,0.f,0.f,0.f};
  #pragma unroll
  for (int nt = 0; nt < 8; ++nt) {
    int n0 = (nbase+nt)*16;
    const __bf16* wp = WT + ((size_t)(n0+col))*256 + quad*8;
    f32x4 acc = zero;
    #pragma unroll
    for (int kk = 0; kk < 8; ++kk) {
      bf16x8 wf = *(const bf16x8*)(wp + kk*32);
      acc = __builtin_amdgcn_mfma_f32_16x16x32_bf16(wf, bq[kk], acc, 0, 0, 0);
    }
    float4 b4 = *(const float4*)(qkvb + n0 + quad*4);
    float bb[4] = {b4.x,b4.y,b4.z,b4.w};
    bf16x4 o;
    #pragma unroll
    for (int r = 0; r < 4; ++r) o[r] = (__bf16)((acc[r]+bb[r])*QSCALE_L2E);
    *(bf16x4*)(qbf + ((size_t)win*16 + col)*256 + n0 + quad*4) = o;
  }
}

// ---------------- local KV: MFMA, block = window, WT tiles LDS-staged ----------------
__global__ __launch_bounds__(256) void loc_kv_mfma(
    const float* __restrict__ F, const __bf16* __restrict__ WT,
    const float* __restrict__ qkvb,
    __bf16* __restrict__ kloc, __bf16* __restrict__ vloct)
{
  __shared__ __bf16 As[64*264];        // 33 KB
  __shared__ __bf16 Bs[3][16*264];     // 24.75 KB
  int bw = blockIdx.x;
  int b = bw >> 8, w = bw & 255;
  int wy4 = ((w >> 4) << 2) - 2, wx4 = ((w & 15) << 2) - 2;
  int tid = threadIdx.x;

  // ---- im2col gather stage ----
  {
    int xp = tid & 3;
    int dy = (tid >> 2) & 7;
    int cg = tid >> 5;
    int yy = wy4 + dy, xx = wx4 + xp*2;
    bool inb = ((unsigned)yy < 64u) && ((unsigned)xx < 64u);
    const float* Fp = F + ((size_t)b*256)*HWSZ + yy*64 + xx;
    #pragma unroll 4
    for (int i = 0; i < 32; ++i) {
      int ch = cg*32 + i;
      float2 v = make_float2(0.f, 0.f);
      if (inb) v = *(const float2*)(Fp + (size_t)ch*HWSZ);
      int t = ch >> 2, r = ch & 3;
      bf16x2 o; o[0] = (__bf16)v.x; o[1] = (__bf16)v.y;
      *(bf16x2*)&As[t*264 + r*64 + dy*8 + xp*2] = o;
    }
  }

  // ---- WT tile staging assignment: thread -> 32 B of one of 16 rows ----
  int brow = tid >> 4, bseg = tid & 15;
  const __bf16* wsrc = WT + ((size_t)(256 + brow))*256 + bseg*16;
  __bf16* bdst = (__bf16*)&Bs[0][0] + brow*264 + bseg*16;

  {
    bf16x8 a0 = *(const bf16x8*)wsrc;
    bf16x8 a1 = *(const bf16x8*)(wsrc + 8);
    *(bf16x8*)bdst = a0;
    *(bf16x8*)(bdst + 8) = a1;
  }
  bf16x8 g0 = *(const bf16x8*)(wsrc + (size_t)1*4096);
  bf16x8 g1 = *(const bf16x8*)(wsrc + (size_t)1*4096 + 8);
  __syncthreads();   // As + Bs[0] ready

  int wv = tid >> 6, lane = tid & 63;
  int col = lane & 15, quad = lane >> 4;
  int m0 = wv*16;
  bf16x8 af[8];
  #pragma unroll
  for (int kk = 0; kk < 8; ++kk)
    af[kk] = *(const bf16x8*)&As[(m0+col)*264 + kk*32 + quad*8];

  const f32x4 zero = {0.f,0.f,0.f,0.f};
  #pragma unroll 1
  for (int nt = 0; nt < 32; ++nt) {
    int buf = nt - (nt/3)*3;           // nt % 3
    bf16x8 n0r, n1r;
    if (nt < 30) {
      const __bf16* p = wsrc + (size_t)(nt+2)*4096;
      n0r = *(const bf16x8*)p; n1r = *(const bf16x8*)(p + 8);
    }
    if (nt < 31) {
      int nb = nt + 1; nb -= (nb/3)*3;
      __bf16* d = (__bf16*)&Bs[0][0] + (size_t)nb*(16*264) + brow*264 + bseg*16;
      *(bf16x8*)d = g0;
      *(bf16x8*)(d + 8) = g1;
    }
    g0 = n0r; g1 = n1r;

    int n = nt*16 + col;
    float bias_n = qkvb[256 + n];
    const __bf16* Bb = (const __bf16*)&Bs[0][0] + (size_t)buf*(16*264);
    f32x4 acc = zero;
    #pragma unroll
    for (int kk = 0; kk < 8; ++kk) {
      bf16x8 bv = *(const bf16x8*)(Bb + col*264 + kk*32 + quad*8);
      acc = __builtin_amdgcn_mfma_f32_16x16x32_bf16(af[kk], bv, acc, 0, 0, 0);
    }
    if (nt < 16) {
      #pragma unroll
      for (int r = 0; r < 4; ++r)
        kloc[((size_t)bw*64 + m0 + quad*4 + r)*256 + n] = (__bf16)(acc[r] + bias_n);
    } else {
      bf16x4 o;
      #pragma unroll
      for (int r = 0; r < 4; ++r) o[r] = (__bf16)(acc[r] + bias_n);
      *(bf16x4*)(vloct + ((size_t)bw*256 + (n - 256))*64 + m0 + quad*4) = o;
    }
    __syncthreads();
  }
}

// ---------------- mid/glb KV: MFMA over token-major mgt ----------------
__global__ __launch_bounds__(256) void mg_kv_mfma(
    const __bf16* __restrict__ mgt, const __bf16* __restrict__ WT,
    const float* __restrict__ qkvb,
    __bf16* __restrict__ kmg, __bf16* __restrict__ vmgt)
{
  int tb = blockIdx.x, nq = blockIdx.y, b = blockIdx.z;
  int tid = threadIdx.x, wv = tid >> 6, lane = tid & 63;
  int col = lane & 15, quad = lane >> 4;
  int m0 = tb*64 + wv*16;
  const __bf16* Ab = mgt + ((size_t)b*1280 + m0 + col)*256 + quad*8;
  bf16x8 af[8];
  #pragma unroll
  for (int kk = 0; kk < 8; ++kk) af[kk] = *(const bf16x8*)(Ab + kk*32);
  const f32x4 zero = {0.f,0.f,0.f,0.f};
  #pragma unroll 2
  for (int nt = nq*8; nt < nq*8 + 8; ++nt) {
    int n = nt*16 + col;                  // 0..511
    float bias_n = qkvb[256 + n];
    const __bf16* Wp = WT + (size_t)(256 + n)*256 + quad*8;
    f32x4 acc = zero;
    #pragma unroll
    for (int kk = 0; kk < 8; ++kk) {
      bf16x8 bv = *(const bf16x8*)(Wp + kk*32);
      acc = __builtin_amdgcn_mfma_f32_16x16x32_bf16(af[kk], bv, acc, 0, 0, 0);
    }
    if (nt < 16) {
      #pragma unroll
      for (int r = 0; r < 4; ++r)
        kmg[((size_t)b*1280 + m0 + quad*4 + r)*256 + n] = (__bf16)(acc[r] + bias_n);
    } else {
      bf16x4 o;
      #pragma unroll
      for (int r = 0; r < 4; ++r) o[r] = (__bf16)(acc[r] + bias_n);
      *(bf16x4*)(vmgt + ((size_t)b*256 + (n - 256))*1280 + m0 + quad*4) = o;
    }
  }
}

// ---------------- MFMA fused attention: LDS K/V staging + 2 windows/wave ----------------
// Block = (b, head, 8 windows), 4 waves x 2 windows. K/V LDS reads amortized over
// 2 windows per wave (the r8 LDS-unit instruction bound), 2 blocks/CU so barriers
// overlap across blocks. Staging: 256 threads x 16 B = the chunk's 4 KB K+V slice.
__global__ __launch_bounds__(256) void attn_mfma(
    const __bf16* __restrict__ qbf, const __bf16* __restrict__ kloc,
    const __bf16* __restrict__ vloct, const __bf16* __restrict__ kmg,
    const __bf16* __restrict__ vmgt, __bf16* __restrict__ obf)
{
  __shared__ __bf16 Ks[3][32][40];      // 7.5 KB
  __shared__ __bf16 Vs[3][32][40];      // 7.5 KB
  __shared__ __bf16 Pb[4][2][2][16][40]; // 20 KB
  int blk = blockIdx.x;                 // b*256 + h*32 + wg
  int b = blk >> 8, rr = blk & 255;
  int h = rr >> 5, wg = rr & 31;
  int tid = threadIdx.x, wv = tid >> 6, lane = tid & 63;
  int col = lane & 15, quad = lane >> 4;
  int bw0 = b*256 + wg*8 + wv*2;        // this wave's two windows: bw0, bw0+1

  // staging: thread -> 16 B of one of 64 rows (32 K rows + 32 V rows)
  int r64 = tid >> 2, seg = tid & 3;
  bool isK = r64 < 32;
  int srow = r64 & 31;
  const __bf16* gbase = isK
      ? kmg  + ((size_t)(b*1280 + srow))*256 + h*32 + seg*8
      : vmgt + ((size_t)(b*256 + h*32 + srow))*1280 + seg*8;
  size_t gstep = isK ? 256 : 1;         // elements per token step
  __bf16* lbase = isK ? &Ks[0][srow][seg*8] : &Vs[0][srow][seg*8];

  bf16x8 aq[2];
  #pragma unroll
  for (int w = 0; w < 2; ++w)
    aq[w] = *(const bf16x8*)(qbf + ((size_t)((bw0+w)*16 + col))*256 + h*32 + quad*8);
  f32x4 O0[2], O1[2];
  const f32x4 zero = {0.f,0.f,0.f,0.f};
  O0[0] = zero; O0[1] = zero; O1[0] = zero; O1[1] = zero;
  float ls[2][4] = {};

  // issue stage load for chunk 2 (tok0 = 0) early
  bf16x8 sreg = *(const bf16x8*)gbase;

  // ---- local chunks 0,1: per-window global loads ----
  #pragma unroll
  for (int w = 0; w < 2; ++w) {
    const __bf16* klocb = kloc  + (size_t)(bw0+w)*16384 + h*32 + quad*8;
    const __bf16* vlocb = vloct + (size_t)(bw0+w)*16384 + (size_t)(h*32)*64 + quad*8;
    #pragma unroll
    for (int ch = 0; ch < 2; ++ch) {
      bf16x8 k0 = *(const bf16x8*)(klocb + (size_t)(ch*32 + col)*256);
      bf16x8 k1 = *(const bf16x8*)(klocb + (size_t)(ch*32 + 16 + col)*256);
      bf16x8 v0 = *(const bf16x8*)(vlocb + (size_t)col*64 + ch*32);
      bf16x8 v1 = *(const bf16x8*)(vlocb + (size_t)(16+col)*64 + ch*32);
      f32x4 S0 = __builtin_amdgcn_mfma_f32_16x16x32_bf16(aq[w], k0, zero, 0, 0, 0);
      f32x4 S1 = __builtin_amdgcn_mfma_f32_16x16x32_bf16(aq[w], k1, zero, 0, 0, 0);
      __bf16* Pw = &Pb[wv][w][ch & 1][0][0];
      #pragma unroll
      for (int r = 0; r < 4; ++r) {
        float p0 = __builtin_amdgcn_exp2f(S0[r]);
        float p1 = __builtin_amdgcn_exp2f(S1[r]);
        ls[w][r] += p0 + p1;
        Pw[(quad*4+r)*40 + col]      = (__bf16)p0;
        Pw[(quad*4+r)*40 + 16 + col] = (__bf16)p1;
      }
      bf16x8 ap = *(const bf16x8*)(Pw + (size_t)col*40 + quad*8);
      O0[w] = __builtin_amdgcn_mfma_f32_16x16x32_bf16(ap, v0, O0[w], 0, 0, 0);
      O1[w] = __builtin_amdgcn_mfma_f32_16x16x32_bf16(ap, v1, O1[w], 0, 0, 0);
    }
  }

  // write chunk-2 slice, issue chunk-3 loads
  *(bf16x8*)(lbase + 2*1280) = sreg;
  sreg = *(const bf16x8*)(gbase + (size_t)32*gstep);
  __syncthreads();

  int buf = 2;
  #pragma unroll 1
  for (int ch = 2; ch < 42; ++ch) {
    int nbuf = (buf == 2) ? 0 : buf + 1;
    if (ch + 1 < 42) {
      *(bf16x8*)(lbase + nbuf*1280) = sreg;             // stage chunk ch+1
      if (ch + 2 < 42)
        sreg = *(const bf16x8*)(gbase + (size_t)(ch*32)*gstep);  // tok0(ch+2)
    }
    const __bf16* Kb = &Ks[buf][0][0];
    const __bf16* Vb = &Vs[buf][0][0];
    bf16x8 k0 = *(const bf16x8*)(Kb + col*40 + quad*8);
    bf16x8 k1 = *(const bf16x8*)(Kb + (16+col)*40 + quad*8);
    bf16x8 v0 = *(const bf16x8*)(Vb + col*40 + quad*8);
    bf16x8 v1 = *(const bf16x8*)(Vb + (16+col)*40 + quad*8);
    #pragma unroll
    for (int w = 0; w < 2; ++w) {
      f32x4 S0 = __builtin_amdgcn_mfma_f32_16x16x32_bf16(aq[w], k0, zero, 0, 0, 0);
      f32x4 S1 = __builtin_amdgcn_mfma_f32_16x16x32_bf16(aq[w], k1, zero, 0, 0, 0);
      __bf16* Pw = &Pb[wv][w][ch & 1][0][0];
      #pragma unroll
      for (int r = 0; r < 4; ++r) {
        float p0 = __builtin_amdgcn_exp2f(S0[r]);
        float p1 = __builtin_amdgcn_exp2f(S1[r]);
        ls[w][r] += p0 + p1;
        Pw[(quad*4+r)*40 + col]      = (__bf16)p0;
        Pw[(quad*4+r)*40 + 16 + col] = (__bf16)p1;
      }
      bf16x8 ap = *(const bf16x8*)(Pw + (size_t)col*40 + quad*8);
      O0[w] = __builtin_amdgcn_mfma_f32_16x16x32_bf16(ap, v0, O0[w], 0, 0, 0);
      O1[w] = __builtin_amdgcn_mfma_f32_16x16x32_bf16(ap, v1, O1[w], 0, 0, 0);
    }
    buf = nbuf;
    __syncthreads();
  }

  #pragma unroll
  for (int w = 0; w < 2; ++w) {
    #pragma unroll
    for (int r = 0; r < 4; ++r) {
      #pragma unroll
      for (int m = 1; m < 16; m <<= 1) ls[w][r] += __shfl_xor(ls[w][r], m);
    }
    __bf16* op = obf + ((size_t)((bw0+w)*16) + quad*4)*256 + h*32 + col;
    #pragma unroll
    for (int r = 0; r < 4; ++r) {
      float inv = 1.f / ls[w][r];
      op[(size_t)r*256]      = (__bf16)(O0[w][r]*inv);
      op[(size_t)r*256 + 16] = (__bf16)(O1[w][r]*inv);
    }
  }
}

// ---------------- out projection, strip version ----------------
__global__ __launch_bounds__(256) void gemm_out_strip(
    const __bf16* __restrict__ obf, const __bf16* __restrict__ WoT,
    const float* __restrict__ outb, const float* __restrict__ Fres,
    float* __restrict__ Out)
{
  __shared__ __bf16 strip[64*264];     // [c64] stride 264, [py] stride 66, [x64]
  int blk = blockIdx.x;                // b*64 + wy*4 + cq
  int b = blk >> 6, wy = (blk >> 2) & 15, cq = blk & 3;
  int c0 = cq*64;
  int tid = threadIdx.x, wv = tid >> 6, lane = tid & 63;
  int col = lane & 15, quad = lane >> 4;
  const f32x4 zero = {0.f,0.f,0.f,0.f};

  #pragma unroll
  for (int i = 0; i < 4; ++i) {
    int wx = wv*4 + i;
    int win = b*256 + wy*16 + wx;
    bf16x8 ao[8];
    const __bf16* op = obf + ((size_t)win*16 + col)*256 + quad*8;
    #pragma unroll
    for (int kk = 0; kk < 8; ++kk) ao[kk] = *(const bf16x8*)(op + kk*32);
    #pragma unroll
    for (int nt = 0; nt < 4; ++nt) {
      int n = c0 + nt*16 + col;
      const __bf16* wp = WoT + ((size_t)n)*256 + quad*8;
      f32x4 acc = zero;
      #pragma unroll
      for (int kk = 0; kk < 8; ++kk) {
        bf16x8 wf = *(const bf16x8*)(wp + kk*32);
        acc = __builtin_amdgcn_mfma_f32_16x16x32_bf16(ao[kk], wf, acc, 0, 0, 0);
      }
      bf16x4 o;
      #pragma unroll
      for (int r = 0; r < 4; ++r) o[r] = (__bf16)acc[r];
      *(bf16x4*)&strip[(nt*16+col)*264 + quad*66 + wx*4] = o;
    }
  }
  __syncthreads();
  #pragma unroll
  for (int j = 0; j < 16; ++j) {
    int f4 = j*256 + tid;               // [c][y][xq]
    int xq = f4 & 15, y = (f4 >> 4) & 3, c = f4 >> 6;
    bf16x4 d = *(const bf16x4*)&strip[c*264 + y*66 + xq*4];
    size_t off = ((size_t)(b*256 + c0 + c))*HWSZ + (wy*4 + y)*64 + xq*4;
    float4 r4 = *(const float4*)(Fres + off);
    float bn = outb[c0 + c];
    float4 o;
    o.x = (float)d[0] + bn + r4.x; o.y = (float)d[1] + bn + r4.y;
    o.z = (float)d[2] + bn + r4.z; o.w = (float)d[3] + bn + r4.w;
    *(float4*)(Out + off) = o;
  }
}

extern "C" void kernel_launch(void* const* d_in, const int* in_sizes, int n_in,
                              void* d_out, int out_size, void* d_ws, size_t ws_size,
                              hipStream_t stream) {
  const float* F     = (const float*)d_in[0];
  const float* qkv_w = (const float*)d_in[1];
  const float* qkv_b = (const float*)d_in[2];
  const float* out_w = (const float*)d_in[3];
  const float* out_b = (const float*)d_in[4];
  const float* ln_w  = (const float*)d_in[5];
  const float* ln_b  = (const float*)d_in[6];
  float* out = (float*)d_out;

  __bf16* qnb   = (__bf16*)d_ws;             // 2,097,152 h
  __bf16* qbf   = qnb   + 2097152;           // 2,097,152 h
  __bf16* obf   = qbf   + 2097152;           // 2,097,152 h
  __bf16* kloc  = obf   + 2097152;           // 8,388,608 h
  __bf16* vloct = kloc  + 8388608;           // 8,388,608 h
  __bf16* kmg   = vloct + 8388608;           // 655,360 h
  __bf16* vmgt  = kmg   + 655360;            // 655,360 h
  __bf16* mgt   = vmgt  + 655360;            // 655,360 h
  __bf16* WT    = mgt   + 655360;            // 196,608 h
  __bf16* WoT   = WT    + 196608;            // 65,536 h
  float*  mid   = (float*)(WoT + 65536);     // 524,288 f
  float*  glb   = mid   + 524288;            // 131,072 f

  transpose_ws<<<dim3(16, 4), 256, 0, stream>>>(qkv_w, out_w, WT, WoT);
  ln_qn_kernel<<<512, 256, 0, stream>>>(F, ln_w, ln_b, qnb);
  pool_kernel<<<512, 256, 0, stream>>>(F, mid, glb);
  transpose_tok<<<dim3(20, 4, 2), 256, 0, stream>>>(mid, glb, mgt);
  gemm_q_mfma<<<256, 256, 0, stream>>>(qnb, WT, qkv_b, qbf);
  loc_kv_mfma<<<512, 256, 0, stream>>>(F, WT, qkv_b, kloc, vloct);
  mg_kv_mfma<<<dim3(20, 4, 2), 256, 0, stream>>>(mgt, WT, qkv_b, kmg, vmgt);
  attn_mfma<<<512, 256, 0, stream>>>(qbf, kloc, vloct, kmg, vmgt, obf);
  gemm_out_strip<<<128, 256, 0, stream>>>(obf, WoT, out_b, F, out);
}